// Round 7
// baseline (200.422 us; speedup 1.0000x reference)
//
#include <hip/hip_runtime.h>
#include <math.h>

#define CCH 128
#define RR  32
#define S_SP 131072   // 32*64*64
#define BATCH 4
#define EPSV 1e-5f

typedef float f32x2 __attribute__((ext_vector_type(2)));

// ws layout (floats):
// [0,1024)       partial sums  s  (1024 half-row blocks)
// [1024,2048)    partial sums  q
// [2048,18432)   w1t[b][c][r] = W1[r][c]*a[b][c]   (r contiguous)
// [18432,18560)  bias[b][r]   = sum_c W1[r][c]*(beta-mean*a)[c]
// [18560,22656)  w2s[c][r]    = W2[c][r]*channel_scale[c]
#define PART_S 0
#define PART_Q 1024
#define W1T_OFF 2048
#define BIAS_OFF 18432
#define W2S_OFF 18560

__global__ __launch_bounds__(256) void stats1_kernel(const float* __restrict__ x,
                                                     float* __restrict__ ws) {
  const int pb = blockIdx.x;               // bc = pb>>1, half = pb&1
  const float* xp = x + (size_t)pb * (S_SP / 2);
  float s = 0.f, q = 0.f;
  for (int i = threadIdx.x * 4; i < S_SP / 2; i += 256 * 4) {
    float4 v = *reinterpret_cast<const float4*>(xp + i);
    s += v.x + v.y + v.z + v.w;
    q += v.x * v.x + v.y * v.y + v.z * v.z + v.w * v.w;
  }
  for (int off = 32; off > 0; off >>= 1) {
    s += __shfl_down(s, off, 64);
    q += __shfl_down(q, off, 64);
  }
  __shared__ float ss[4], qq[4];
  const int wave = threadIdx.x >> 6, lane = threadIdx.x & 63;
  if (lane == 0) { ss[wave] = s; qq[wave] = q; }
  __syncthreads();
  if (threadIdx.x == 0) {
    ws[PART_S + pb] = ss[0] + ss[1] + ss[2] + ss[3];
    ws[PART_Q + pb] = qq[0] + qq[1] + qq[2] + qq[3];
  }
}

__global__ __launch_bounds__(256) void prep_kernel(const float* __restrict__ W1,
                                                   const float* __restrict__ W2,
                                                   const float* __restrict__ scale,
                                                   const float* __restrict__ gamma,
                                                   const float* __restrict__ beta,
                                                   float* __restrict__ ws) {
  const int b = blockIdx.x;
  __shared__ float aS[CCH], bbS[CCH];
  if (threadIdx.x < CCH) {
    const int c = threadIdx.x;
    const int bc = b * CCH + c;
    const float S = ws[PART_S + 2 * bc] + ws[PART_S + 2 * bc + 1];
    const float Q = ws[PART_Q + 2 * bc] + ws[PART_Q + 2 * bc + 1];
    const float mean = S / (float)S_SP;
    const float var  = Q / (float)S_SP - mean * mean;    // biased, matches ref
    const float rstd = rsqrtf(var + EPSV);
    const float a = rstd * gamma[c];
    aS[c]  = a;
    bbS[c] = beta[c] - mean * a;
  }
  __syncthreads();
  float* w1t = ws + W1T_OFF + b * CCH * RR;
  for (int idx = threadIdx.x; idx < CCH * RR; idx += 256) {
    const int c = idx >> 5, r = idx & 31;
    w1t[idx] = W1[r * CCH + c] * aS[c];
  }
  if (threadIdx.x < RR) {
    const int r = threadIdx.x;
    float sum = 0.f;
    for (int c = 0; c < CCH; ++c) sum += W1[r * CCH + c] * bbS[c];
    ws[BIAS_OFF + b * RR + r] = sum;
  }
  if (b == 0) {
    for (int idx = threadIdx.x; idx < CCH * RR; idx += 256) {
      const int c = idx >> 5;
      ws[W2S_OFF + idx] = W2[idx] * scale[c];   // W2 is (C,R) row-major
    }
  }
}

// 2 consecutive positions per thread (float2), 64 fp32 accumulators.
// Weights from global with wave-uniform addresses (scalarized to s_load).
// Depth-8 x-load software pipeline with NAMED registers: per-wave latency
// window = 8 c-iters x 32 cyc x 4 waves/SIMD ~ 1024 cyc > ~900 cyc HBM miss.
__global__ __launch_bounds__(256, 4) void mlp_kernel(const float* __restrict__ x,
                                                     const float* __restrict__ ws,
                                                     float* __restrict__ out) {
  const int b = blockIdx.y;
  const int s = (blockIdx.x * 256 + threadIdx.x) * 2;
  const float* xc = x + (size_t)b * CCH * S_SP + s;
  float*       oc = out + (size_t)b * CCH * S_SP + s;

  const float4* w1g4 = reinterpret_cast<const float4*>(ws + W1T_OFF + (size_t)b * CCH * RR);
  const float4* w2g4 = reinterpret_cast<const float4*>(ws + W2S_OFF);
  const float*  bias = ws + BIAS_OFF + b * RR;

  float p0[RR], p1[RR];
  #pragma unroll
  for (int r = 0; r < RR; ++r) { const float bv = bias[r]; p0[r] = bv; p1[r] = bv; }

#define LDX(c) (*reinterpret_cast<const float2*>(xc + (size_t)(c) * S_SP))

#define FMA1(c, v)                                                        \
  {                                                                       \
    _Pragma("unroll")                                                     \
    for (int rq = 0; rq < RR / 4; ++rq) {                                 \
      const float4 w = w1g4[(c) * (RR / 4) + rq];                         \
      p0[4*rq+0] = fmaf((v).x, w.x, p0[4*rq+0]);                          \
      p0[4*rq+1] = fmaf((v).x, w.y, p0[4*rq+1]);                          \
      p0[4*rq+2] = fmaf((v).x, w.z, p0[4*rq+2]);                          \
      p0[4*rq+3] = fmaf((v).x, w.w, p0[4*rq+3]);                          \
      p1[4*rq+0] = fmaf((v).y, w.x, p1[4*rq+0]);                          \
      p1[4*rq+1] = fmaf((v).y, w.y, p1[4*rq+1]);                          \
      p1[4*rq+2] = fmaf((v).y, w.z, p1[4*rq+2]);                          \
      p1[4*rq+3] = fmaf((v).y, w.w, p1[4*rq+3]);                          \
    }                                                                     \
  }

  // ---- pass 1: proj = w1t @ x + bias, depth-8 pipeline ----
  {
    float2 v0 = LDX(0), v1 = LDX(1), v2 = LDX(2), v3 = LDX(3);
    float2 v4 = LDX(4), v5 = LDX(5), v6 = LDX(6), v7 = LDX(7);
    for (int c8 = 0; c8 < 15; ++c8) {
      const int c = c8 * 8;
      FMA1(c + 0, v0); v0 = LDX(c +  8);
      FMA1(c + 1, v1); v1 = LDX(c +  9);
      FMA1(c + 2, v2); v2 = LDX(c + 10);
      FMA1(c + 3, v3); v3 = LDX(c + 11);
      FMA1(c + 4, v4); v4 = LDX(c + 12);
      FMA1(c + 5, v5); v5 = LDX(c + 13);
      FMA1(c + 6, v6); v6 = LDX(c + 14);
      FMA1(c + 7, v7); v7 = LDX(c + 15);
    }
    FMA1(120, v0); FMA1(121, v1); FMA1(122, v2); FMA1(123, v3);
    FMA1(124, v4); FMA1(125, v5); FMA1(126, v6); FMA1(127, v7);
  }

  #pragma unroll
  for (int r = 0; r < RR; ++r) {
    p0[r] = fminf(fmaxf(p0[r], 0.f), 6.f);
    p1[r] = fminf(fmaxf(p1[r], 0.f), 6.f);
  }

#define FMA2(c, v)                                                        \
  {                                                                       \
    float r0 = 0.f, r1 = 0.f;                                             \
    _Pragma("unroll")                                                     \
    for (int rq = 0; rq < RR / 4; ++rq) {                                 \
      const float4 w = w2g4[(c) * (RR / 4) + rq];                         \
      r0 = fmaf(p0[4*rq+0], w.x, r0);                                     \
      r0 = fmaf(p0[4*rq+1], w.y, r0);                                     \
      r0 = fmaf(p0[4*rq+2], w.z, r0);                                     \
      r0 = fmaf(p0[4*rq+3], w.w, r0);                                     \
      r1 = fmaf(p1[4*rq+0], w.x, r1);                                     \
      r1 = fmaf(p1[4*rq+1], w.y, r1);                                     \
      r1 = fmaf(p1[4*rq+2], w.z, r1);                                     \
      r1 = fmaf(p1[4*rq+3], w.w, r1);                                     \
    }                                                                     \
    f32x2 o_; o_.x = r0 + (v).x; o_.y = r1 + (v).y;                       \
    __builtin_nontemporal_store(o_,                                       \
        reinterpret_cast<f32x2*>(oc + (size_t)(c) * S_SP));               \
  }

  // ---- pass 2: out = w2s @ act + x, depth-8 pipeline ----
  {
    float2 v0 = LDX(0), v1 = LDX(1), v2 = LDX(2), v3 = LDX(3);
    float2 v4 = LDX(4), v5 = LDX(5), v6 = LDX(6), v7 = LDX(7);
    for (int c8 = 0; c8 < 15; ++c8) {
      const int c = c8 * 8;
      FMA2(c + 0, v0); v0 = LDX(c +  8);
      FMA2(c + 1, v1); v1 = LDX(c +  9);
      FMA2(c + 2, v2); v2 = LDX(c + 10);
      FMA2(c + 3, v3); v3 = LDX(c + 11);
      FMA2(c + 4, v4); v4 = LDX(c + 12);
      FMA2(c + 5, v5); v5 = LDX(c + 13);
      FMA2(c + 6, v6); v6 = LDX(c + 14);
      FMA2(c + 7, v7); v7 = LDX(c + 15);
    }
    FMA2(120, v0); FMA2(121, v1); FMA2(122, v2); FMA2(123, v3);
    FMA2(124, v4); FMA2(125, v5); FMA2(126, v6); FMA2(127, v7);
  }
}

extern "C" void kernel_launch(void* const* d_in, const int* in_sizes, int n_in,
                              void* d_out, int out_size, void* d_ws, size_t ws_size,
                              hipStream_t stream) {
  const float* x     = (const float*)d_in[0];
  const float* scale = (const float*)d_in[1];
  const float* W1    = (const float*)d_in[2];
  const float* W2    = (const float*)d_in[3];
  const float* gamma = (const float*)d_in[4];
  const float* beta  = (const float*)d_in[5];
  float* out = (float*)d_out;
  float* ws  = (float*)d_ws;

  stats1_kernel<<<BATCH * CCH * 2, 256, 0, stream>>>(x, ws);
  prep_kernel<<<BATCH, 256, 0, stream>>>(W1, W2, scale, gamma, beta, ws);
  dim3 grid(S_SP / (256 * 2), BATCH);
  mlp_kernel<<<grid, 256, 0, stream>>>(x, ws, out);
}

// Round 8
// 183.264 us; speedup vs baseline: 1.0936x; 1.0936x over previous
//
#include <hip/hip_runtime.h>
#include <math.h>

#define CCH 128
#define RR  32
#define S_SP 131072   // 32*64*64
#define BATCH 4
#define EPSV 1e-5f

typedef float f32x4 __attribute__((ext_vector_type(4)));

// ws layout (floats):
// [0,1024)       partial sums  s  (1024 half-row blocks)
// [1024,2048)    partial sums  q
// [2048,18432)   w1t[b][c][r] = W1[r][c]*a[b][c]   (r contiguous)
// [18432,18560)  bias[b][r]   = sum_c W1[r][c]*(beta-mean*a)[c]
// [18560,22656)  w2s[c][r]    = W2[c][r]*channel_scale[c]
#define PART_S 0
#define PART_Q 1024
#define W1T_OFF 2048
#define BIAS_OFF 18432
#define W2S_OFF 18560

__global__ __launch_bounds__(256) void stats1_kernel(const float* __restrict__ x,
                                                     float* __restrict__ ws) {
  const int pb = blockIdx.x;               // bc = pb>>1, half = pb&1
  const float* xp = x + (size_t)pb * (S_SP / 2);
  float s = 0.f, q = 0.f;
  for (int i = threadIdx.x * 4; i < S_SP / 2; i += 256 * 4) {
    float4 v = *reinterpret_cast<const float4*>(xp + i);
    s += v.x + v.y + v.z + v.w;
    q += v.x * v.x + v.y * v.y + v.z * v.z + v.w * v.w;
  }
  for (int off = 32; off > 0; off >>= 1) {
    s += __shfl_down(s, off, 64);
    q += __shfl_down(q, off, 64);
  }
  __shared__ float ss[4], qq[4];
  const int wave = threadIdx.x >> 6, lane = threadIdx.x & 63;
  if (lane == 0) { ss[wave] = s; qq[wave] = q; }
  __syncthreads();
  if (threadIdx.x == 0) {
    ws[PART_S + pb] = ss[0] + ss[1] + ss[2] + ss[3];
    ws[PART_Q + pb] = qq[0] + qq[1] + qq[2] + qq[3];
  }
}

__global__ __launch_bounds__(256) void prep_kernel(const float* __restrict__ W1,
                                                   const float* __restrict__ W2,
                                                   const float* __restrict__ scale,
                                                   const float* __restrict__ gamma,
                                                   const float* __restrict__ beta,
                                                   float* __restrict__ ws) {
  const int b = blockIdx.x;
  __shared__ float aS[CCH], bbS[CCH];
  if (threadIdx.x < CCH) {
    const int c = threadIdx.x;
    const int bc = b * CCH + c;
    const float S = ws[PART_S + 2 * bc] + ws[PART_S + 2 * bc + 1];
    const float Q = ws[PART_Q + 2 * bc] + ws[PART_Q + 2 * bc + 1];
    const float mean = S / (float)S_SP;
    const float var  = Q / (float)S_SP - mean * mean;    // biased, matches ref
    const float rstd = rsqrtf(var + EPSV);
    const float a = rstd * gamma[c];
    aS[c]  = a;
    bbS[c] = beta[c] - mean * a;
  }
  __syncthreads();
  float* w1t = ws + W1T_OFF + b * CCH * RR;
  for (int idx = threadIdx.x; idx < CCH * RR; idx += 256) {
    const int c = idx >> 5, r = idx & 31;
    w1t[idx] = W1[r * CCH + c] * aS[c];
  }
  if (threadIdx.x < RR) {
    const int r = threadIdx.x;
    float sum = 0.f;
    for (int c = 0; c < CCH; ++c) sum += W1[r * CCH + c] * bbS[c];
    ws[BIAS_OFF + b * RR + r] = sum;
  }
  if (b == 0) {
    for (int idx = threadIdx.x; idx < CCH * RR; idx += 256) {
      const int c = idx >> 5;
      ws[W2S_OFF + idx] = W2[idx] * scale[c];   // W2 is (C,R) row-major
    }
  }
}

// Block = 128 threads (2 waves), 4 consecutive positions per thread (float4
// loads/stores: 1KB per wave-instruction). Grid = 1024 blocks -> 8 blocks/CU,
// 16 waves/CU (VGPR permitting). Weights from global with wave-uniform
// addresses (scalarized to s_load, SGPR operand in v_fma). No LDS. Depth-4
// x-load pipeline with named registers; nontemporal float4 stores.
__global__ __launch_bounds__(128) void mlp_kernel(const float* __restrict__ x,
                                                  const float* __restrict__ ws,
                                                  float* __restrict__ out) {
  const int b = blockIdx.y;
  const int s = (blockIdx.x * 128 + threadIdx.x) * 4;
  const float* xc = x + (size_t)b * CCH * S_SP + s;
  float*       oc = out + (size_t)b * CCH * S_SP + s;

  const float4* w1g4 = reinterpret_cast<const float4*>(ws + W1T_OFF + (size_t)b * CCH * RR);
  const float4* w2g4 = reinterpret_cast<const float4*>(ws + W2S_OFF);
  const float*  bias = ws + BIAS_OFF + b * RR;

  float p0[RR], p1[RR], p2[RR], p3[RR];
  #pragma unroll
  for (int r = 0; r < RR; ++r) {
    const float bv = bias[r];
    p0[r] = bv; p1[r] = bv; p2[r] = bv; p3[r] = bv;
  }

#define LDX(c) (*reinterpret_cast<const float4*>(xc + (size_t)(c) * S_SP))

#define FMA1(c, v)                                                        \
  {                                                                       \
    _Pragma("unroll")                                                     \
    for (int rq = 0; rq < RR / 4; ++rq) {                                 \
      const float4 w = w1g4[(c) * (RR / 4) + rq];                         \
      p0[4*rq+0] = fmaf((v).x, w.x, p0[4*rq+0]);                          \
      p0[4*rq+1] = fmaf((v).x, w.y, p0[4*rq+1]);                          \
      p0[4*rq+2] = fmaf((v).x, w.z, p0[4*rq+2]);                          \
      p0[4*rq+3] = fmaf((v).x, w.w, p0[4*rq+3]);                          \
      p1[4*rq+0] = fmaf((v).y, w.x, p1[4*rq+0]);                          \
      p1[4*rq+1] = fmaf((v).y, w.y, p1[4*rq+1]);                          \
      p1[4*rq+2] = fmaf((v).y, w.z, p1[4*rq+2]);                          \
      p1[4*rq+3] = fmaf((v).y, w.w, p1[4*rq+3]);                          \
      p2[4*rq+0] = fmaf((v).z, w.x, p2[4*rq+0]);                          \
      p2[4*rq+1] = fmaf((v).z, w.y, p2[4*rq+1]);                          \
      p2[4*rq+2] = fmaf((v).z, w.z, p2[4*rq+2]);                          \
      p2[4*rq+3] = fmaf((v).z, w.w, p2[4*rq+3]);                          \
      p3[4*rq+0] = fmaf((v).w, w.x, p3[4*rq+0]);                          \
      p3[4*rq+1] = fmaf((v).w, w.y, p3[4*rq+1]);                          \
      p3[4*rq+2] = fmaf((v).w, w.z, p3[4*rq+2]);                          \
      p3[4*rq+3] = fmaf((v).w, w.w, p3[4*rq+3]);                          \
    }                                                                     \
  }

  // ---- pass 1: proj = w1t @ x + bias, depth-4 pipeline ----
  {
    float4 v0 = LDX(0), v1 = LDX(1), v2 = LDX(2), v3 = LDX(3);
    for (int c4 = 0; c4 < 31; ++c4) {
      const int c = c4 * 4;
      FMA1(c + 0, v0); v0 = LDX(c + 4);
      FMA1(c + 1, v1); v1 = LDX(c + 5);
      FMA1(c + 2, v2); v2 = LDX(c + 6);
      FMA1(c + 3, v3); v3 = LDX(c + 7);
    }
    FMA1(124, v0); FMA1(125, v1); FMA1(126, v2); FMA1(127, v3);
  }

  #pragma unroll
  for (int r = 0; r < RR; ++r) {
    p0[r] = fminf(fmaxf(p0[r], 0.f), 6.f);
    p1[r] = fminf(fmaxf(p1[r], 0.f), 6.f);
    p2[r] = fminf(fmaxf(p2[r], 0.f), 6.f);
    p3[r] = fminf(fmaxf(p3[r], 0.f), 6.f);
  }

#define FMA2(c, v)                                                        \
  {                                                                       \
    float r0 = 0.f, r1 = 0.f, r2 = 0.f, r3 = 0.f;                         \
    _Pragma("unroll")                                                     \
    for (int rq = 0; rq < RR / 4; ++rq) {                                 \
      const float4 w = w2g4[(c) * (RR / 4) + rq];                         \
      r0 = fmaf(p0[4*rq+0], w.x, r0);                                     \
      r0 = fmaf(p0[4*rq+1], w.y, r0);                                     \
      r0 = fmaf(p0[4*rq+2], w.z, r0);                                     \
      r0 = fmaf(p0[4*rq+3], w.w, r0);                                     \
      r1 = fmaf(p1[4*rq+0], w.x, r1);                                     \
      r1 = fmaf(p1[4*rq+1], w.y, r1);                                     \
      r1 = fmaf(p1[4*rq+2], w.z, r1);                                     \
      r1 = fmaf(p1[4*rq+3], w.w, r1);                                     \
      r2 = fmaf(p2[4*rq+0], w.x, r2);                                     \
      r2 = fmaf(p2[4*rq+1], w.y, r2);                                     \
      r2 = fmaf(p2[4*rq+2], w.z, r2);                                     \
      r2 = fmaf(p2[4*rq+3], w.w, r2);                                     \
      r3 = fmaf(p3[4*rq+0], w.x, r3);                                     \
      r3 = fmaf(p3[4*rq+1], w.y, r3);                                     \
      r3 = fmaf(p3[4*rq+2], w.z, r3);                                     \
      r3 = fmaf(p3[4*rq+3], w.w, r3);                                     \
    }                                                                     \
    f32x4 o_;                                                             \
    o_.x = r0 + (v).x; o_.y = r1 + (v).y;                                 \
    o_.z = r2 + (v).z; o_.w = r3 + (v).w;                                 \
    __builtin_nontemporal_store(o_,                                       \
        reinterpret_cast<f32x4*>(oc + (size_t)(c) * S_SP));               \
  }

  // ---- pass 2: out = w2s @ act + x, depth-4 pipeline ----
  {
    float4 v0 = LDX(0), v1 = LDX(1), v2 = LDX(2), v3 = LDX(3);
    for (int c4 = 0; c4 < 31; ++c4) {
      const int c = c4 * 4;
      FMA2(c + 0, v0); v0 = LDX(c + 4);
      FMA2(c + 1, v1); v1 = LDX(c + 5);
      FMA2(c + 2, v2); v2 = LDX(c + 6);
      FMA2(c + 3, v3); v3 = LDX(c + 7);
    }
    FMA2(124, v0); FMA2(125, v1); FMA2(126, v2); FMA2(127, v3);
  }
}

extern "C" void kernel_launch(void* const* d_in, const int* in_sizes, int n_in,
                              void* d_out, int out_size, void* d_ws, size_t ws_size,
                              hipStream_t stream) {
  const float* x     = (const float*)d_in[0];
  const float* scale = (const float*)d_in[1];
  const float* W1    = (const float*)d_in[2];
  const float* W2    = (const float*)d_in[3];
  const float* gamma = (const float*)d_in[4];
  const float* beta  = (const float*)d_in[5];
  float* out = (float*)d_out;
  float* ws  = (float*)d_ws;

  stats1_kernel<<<BATCH * CCH * 2, 256, 0, stream>>>(x, ws);
  prep_kernel<<<BATCH, 256, 0, stream>>>(W1, W2, scale, gamma, beta, ws);
  dim3 grid(S_SP / (128 * 4), BATCH);
  mlp_kernel<<<grid, 128, 0, stream>>>(x, ws, out);
}

// Round 9
// 155.166 us; speedup vs baseline: 1.2917x; 1.1811x over previous
//
#include <hip/hip_runtime.h>
#include <math.h>
#include <stdint.h>

#define CCH 128
#define RR  32
#define S_SP 131072   // 32*64*64
#define BATCH 4
#define EPSV 1e-5f

typedef float f32x4 __attribute__((ext_vector_type(4)));
typedef short bf16x8 __attribute__((ext_vector_type(8)));

// ws layout (total 90624 B, fits the previously-proven footprint exactly):
// floats: [0,1024) PART_S, [1024,2048) PART_Q, [2048,2176) bias[b][32]
// bytes : W1F at 8704  : [b][kk][m][s][lane][j] ushort (8192/batch, 16384 B/batch, 4 batches)
//         W2F at 74240 : [m][s][lane][j] ushort (8192, 16384 B)
#define PART_S 0
#define PART_Q 1024
#define BIAS_F 2048
#define W1F_BYTE 8704
#define W2F_BYTE 74240

__device__ __forceinline__ unsigned short bf16rne(float f) {
  return __builtin_bit_cast(unsigned short, (__bf16)f);
}

__global__ __launch_bounds__(256) void stats1_kernel(const float* __restrict__ x,
                                                     float* __restrict__ ws) {
  const int pb = blockIdx.x;
  const float* xp = x + (size_t)pb * (S_SP / 2);
  float s = 0.f, q = 0.f;
  for (int i = threadIdx.x * 4; i < S_SP / 2; i += 256 * 4) {
    float4 v = *reinterpret_cast<const float4*>(xp + i);
    s += v.x + v.y + v.z + v.w;
    q += v.x * v.x + v.y * v.y + v.z * v.z + v.w * v.w;
  }
  for (int off = 32; off > 0; off >>= 1) {
    s += __shfl_down(s, off, 64);
    q += __shfl_down(q, off, 64);
  }
  __shared__ float ss[4], qq[4];
  const int wave = threadIdx.x >> 6, lane = threadIdx.x & 63;
  if (lane == 0) { ss[wave] = s; qq[wave] = q; }
  __syncthreads();
  if (threadIdx.x == 0) {
    ws[PART_S + pb] = ss[0] + ss[1] + ss[2] + ss[3];
    ws[PART_Q + pb] = qq[0] + qq[1] + qq[2] + qq[3];
  }
}

// blocks 0..3: per-batch a/bb, bias, W1 fragments (normalization folded in).
// block 4: W2 fragments (scaled), batch-independent.
__global__ __launch_bounds__(256) void prep_kernel(const float* __restrict__ W1,
                                                   const float* __restrict__ W2,
                                                   const float* __restrict__ scale,
                                                   const float* __restrict__ gamma,
                                                   const float* __restrict__ beta,
                                                   float* __restrict__ ws) {
  const int blk = blockIdx.x;
  if (blk == 4) {
    unsigned short* w2f = (unsigned short*)((char*)ws + W2F_BYTE);
    for (int e = threadIdx.x; e < 8192; e += 256) {
      const int j = e & 7, lane = (e >> 3) & 63, s = (e >> 9) & 1, m = e >> 10;
      const int c = 16 * m + (lane & 15);
      const int r = (lane >> 4) * 8 + j;
      const float w = W2[c * RR + r] * scale[c];
      const uint32_t bits = __float_as_uint(w);
      if (s == 0) {
        w2f[e] = (unsigned short)(bits >> 16);           // trunc-hi
      } else {
        const float rem = w - __uint_as_float(bits & 0xffff0000u);
        w2f[e] = bf16rne(rem);                           // exact remainder
      }
    }
    return;
  }
  const int b = blk;
  __shared__ float aS[CCH], bbS[CCH];
  if (threadIdx.x < CCH) {
    const int c = threadIdx.x;
    const int bc = b * CCH + c;
    const float S = ws[PART_S + 2 * bc] + ws[PART_S + 2 * bc + 1];
    const float Q = ws[PART_Q + 2 * bc] + ws[PART_Q + 2 * bc + 1];
    const float mean = S / (float)S_SP;
    const float var  = Q / (float)S_SP - mean * mean;    // biased, matches ref
    const float rstd = rsqrtf(var + EPSV);
    const float a = rstd * gamma[c];
    aS[c]  = a;
    bbS[c] = beta[c] - mean * a;
  }
  __syncthreads();
  unsigned short* w1f = (unsigned short*)((char*)ws + W1F_BYTE + b * 16384);
  for (int e = threadIdx.x; e < 8192; e += 256) {
    const int j = e & 7, lane = (e >> 3) & 63, s = (e >> 9) & 1;
    const int m = (e >> 10) & 1, kk = e >> 11;
    const int r = 16 * m + (lane & 15);
    const int c = kk * 32 + (lane >> 4) * 8 + j;
    const float w = W1[r * CCH + c] * aS[c];
    const uint32_t bits = __float_as_uint(w);
    if (s == 0) {
      w1f[e] = (unsigned short)(bits >> 16);
    } else {
      const float rem = w - __uint_as_float(bits & 0xffff0000u);
      w1f[e] = bf16rne(rem);
    }
  }
  if (threadIdx.x < RR) {
    const int r = threadIdx.x;
    float sum = 0.f;
    for (int c = 0; c < CCH; ++c) sum += W1[r * CCH + c] * bbS[c];
    ws[BIAS_F + b * RR + r] = sum;
  }
}

// MFMA MLP: block = 256 thr (4 waves), tile = all 128 c x 64 positions.
// GEMM1: proj(32xN) = W1a(32x128) @ x(128xN); GEMM2: rec(128xN) = W2s(128x32) @ act.
// Split-precision bf16 (hi + exact-lo), 3-term MFMA per product ~= fp32.
// LDS: xs 32KB + act 8KB = 40960 -> 4 blocks/CU.
__global__ __launch_bounds__(256, 4) void mlp_kernel(const float* __restrict__ x,
                                                     const float* __restrict__ ws,
                                                     float* __restrict__ out) {
  const int b = blockIdx.y;
  const int n0 = blockIdx.x * 64;
  const int tid = threadIdx.x;
  const int wave = tid >> 6, lane = tid & 63;
  const int g = lane >> 4, cl = lane & 15;
  const int bcol = wave * 16 + cl;

  __shared__ float xs[CCH][64];
  __shared__ uint32_t act32[4][RR * 16];

  const float* xb = x + (size_t)b * CCH * S_SP;

  // ---- A1 (W1) fragment loads: issued first, latency hides under staging ----
  const unsigned short* w1f = (const unsigned short*)((const char*)ws + W1F_BYTE + b * 16384);
  bf16x8 a1[4][2][2];   // [kk][m][split]
  #pragma unroll
  for (int kk = 0; kk < 4; ++kk)
    #pragma unroll
    for (int m = 0; m < 2; ++m)
      #pragma unroll
      for (int s = 0; s < 2; ++s)
        a1[kk][m][s] = *reinterpret_cast<const bf16x8*>(
            w1f + (size_t)(((kk * 2 + m) * 2 + s) * 64 + lane) * 8);

  // ---- bias -> acc1 init (C-in of MFMA) ----
  const float* biasp = ws + BIAS_F + b * RR;
  f32x4 acc1[2];
  #pragma unroll
  for (int m = 0; m < 2; ++m)
    #pragma unroll
    for (int q = 0; q < 4; ++q)
      acc1[m][q] = biasp[16 * m + 4 * g + q];

  // ---- stage x tile (fp32) into LDS, coalesced float4 ----
  #pragma unroll
  for (int k = 0; k < 8; ++k) {
    const int i = tid + 256 * k;          // float4 index in tile
    const int row = i >> 4, c16 = i & 15;
    f32x4 v = *reinterpret_cast<const f32x4*>(xb + (size_t)row * S_SP + n0 + c16 * 4);
    *reinterpret_cast<f32x4*>(&xs[row][c16 * 4]) = v;
  }
  __syncthreads();

  // ---- GEMM1: 4 K-steps of 32, split B built on the fly ----
  #pragma unroll
  for (int kk = 0; kk < 4; ++kk) {
    float e[8];
    #pragma unroll
    for (int j = 0; j < 8; ++j) e[j] = xs[kk * 32 + g * 8 + j][bcol];
    union { uint32_t u[4]; bf16x8 v; } bh, bl;
    #pragma unroll
    for (int jp = 0; jp < 4; ++jp) {
      const uint32_t u0 = __float_as_uint(e[2 * jp]);
      const uint32_t u1 = __float_as_uint(e[2 * jp + 1]);
      bh.u[jp] = __builtin_amdgcn_perm(u1, u0, 0x07060302u);   // [hi16(e1):hi16(e0)]
      const float l0 = e[2 * jp]     - __uint_as_float(u0 & 0xffff0000u);
      const float l1 = e[2 * jp + 1] - __uint_as_float(u1 & 0xffff0000u);
      bl.u[jp] = (uint32_t)bf16rne(l0) | ((uint32_t)bf16rne(l1) << 16);
    }
    #pragma unroll
    for (int m = 0; m < 2; ++m) {
      acc1[m] = __builtin_amdgcn_mfma_f32_16x16x32_bf16(a1[kk][m][1], bh.v, acc1[m], 0, 0, 0);
      acc1[m] = __builtin_amdgcn_mfma_f32_16x16x32_bf16(a1[kk][m][0], bl.v, acc1[m], 0, 0, 0);
      acc1[m] = __builtin_amdgcn_mfma_f32_16x16x32_bf16(a1[kk][m][0], bh.v, acc1[m], 0, 0, 0);
    }
  }

  // ---- ReLU6, split act to (hi<<16)|lo, exchange through LDS ----
  #pragma unroll
  for (int m = 0; m < 2; ++m)
    #pragma unroll
    for (int q = 0; q < 4; ++q) {
      const float a = fminf(fmaxf(acc1[m][q], 0.f), 6.f);
      const uint32_t u = __float_as_uint(a);
      const float rem = a - __uint_as_float(u & 0xffff0000u);
      const uint32_t lob = (uint32_t)bf16rne(rem);
      const int r = 16 * m + 4 * g + q;
      act32[wave][r * 16 + cl] = (u & 0xffff0000u) | lob;   // hi in top16, lo in low16
    }
  __syncthreads();

  // ---- GEMM2 B-frag: act rows k = g*8+j at col cl ----
  uint32_t ua[8];
  #pragma unroll
  for (int j = 0; j < 8; ++j) ua[j] = act32[wave][(g * 8 + j) * 16 + cl];
  union { uint32_t u[4]; bf16x8 v; } bh2, bl2;
  #pragma unroll
  for (int jp = 0; jp < 4; ++jp) {
    bh2.u[jp] = __builtin_amdgcn_perm(ua[2 * jp + 1], ua[2 * jp], 0x07060302u);
    bl2.u[jp] = __builtin_amdgcn_perm(ua[2 * jp + 1], ua[2 * jp], 0x05040100u);
  }

  // ---- GEMM2 + fused epilogue (residual + store), per 16-row tile ----
  const unsigned short* w2f = (const unsigned short*)((const char*)ws + W2F_BYTE);
  float* ob = out + (size_t)b * CCH * S_SP + n0 + bcol;
  #pragma unroll
  for (int m = 0; m < 8; ++m) {
    const bf16x8 ah = *reinterpret_cast<const bf16x8*>(w2f + (size_t)((m * 2 + 0) * 64 + lane) * 8);
    const bf16x8 al = *reinterpret_cast<const bf16x8*>(w2f + (size_t)((m * 2 + 1) * 64 + lane) * 8);
    f32x4 acc = {0.f, 0.f, 0.f, 0.f};
    acc = __builtin_amdgcn_mfma_f32_16x16x32_bf16(al, bh2.v, acc, 0, 0, 0);
    acc = __builtin_amdgcn_mfma_f32_16x16x32_bf16(ah, bl2.v, acc, 0, 0, 0);
    acc = __builtin_amdgcn_mfma_f32_16x16x32_bf16(ah, bh2.v, acc, 0, 0, 0);
    #pragma unroll
    for (int q = 0; q < 4; ++q) {
      const int c = 16 * m + 4 * g + q;
      const float o = acc[q] + xs[c][bcol];
      __builtin_nontemporal_store(o, ob + (size_t)c * S_SP);
    }
  }
}

extern "C" void kernel_launch(void* const* d_in, const int* in_sizes, int n_in,
                              void* d_out, int out_size, void* d_ws, size_t ws_size,
                              hipStream_t stream) {
  const float* x     = (const float*)d_in[0];
  const float* scale = (const float*)d_in[1];
  const float* W1    = (const float*)d_in[2];
  const float* W2    = (const float*)d_in[3];
  const float* gamma = (const float*)d_in[4];
  const float* beta  = (const float*)d_in[5];
  float* out = (float*)d_out;
  float* ws  = (float*)d_ws;

  stats1_kernel<<<BATCH * CCH * 2, 256, 0, stream>>>(x, ws);
  prep_kernel<<<5, 256, 0, stream>>>(W1, W2, scale, gamma, beta, ws);
  dim3 grid(S_SP / 64, BATCH);
  mlp_kernel<<<grid, 256, 0, stream>>>(x, ws, out);
}

// Round 10
// 151.268 us; speedup vs baseline: 1.3249x; 1.0258x over previous
//
#include <hip/hip_runtime.h>
#include <math.h>
#include <stdint.h>

#define CCH 128
#define RR  32
#define S_SP 131072   // 32*64*64
#define BATCH 4
#define EPSV 1e-5f

typedef float f32x4 __attribute__((ext_vector_type(4)));
typedef short bf16x8 __attribute__((ext_vector_type(8)));

// ws layout:
// floats: [0,1024) PART_S, [1024,2048) PART_Q, [2048,2176) bias[b][32]
// bytes : W1F at 8704  : [b][kk][m][lane][j] bf16, 8192 B per batch (4 batches)
//         W2F at 41472 : [m][lane][j] bf16, 8192 B
#define PART_S 0
#define PART_Q 1024
#define BIAS_F 2048
#define W1F_BYTE 8704
#define W2F_BYTE 41472

__device__ __forceinline__ unsigned short bf16rne(float f) {
  return __builtin_bit_cast(unsigned short, (__bf16)f);
}

__global__ __launch_bounds__(256) void stats1_kernel(const float* __restrict__ x,
                                                     float* __restrict__ ws) {
  const int pb = blockIdx.x;
  const float* xp = x + (size_t)pb * (S_SP / 2);
  float s = 0.f, q = 0.f;
  for (int i = threadIdx.x * 4; i < S_SP / 2; i += 256 * 4) {
    float4 v = *reinterpret_cast<const float4*>(xp + i);
    s += v.x + v.y + v.z + v.w;
    q += v.x * v.x + v.y * v.y + v.z * v.z + v.w * v.w;
  }
  for (int off = 32; off > 0; off >>= 1) {
    s += __shfl_down(s, off, 64);
    q += __shfl_down(q, off, 64);
  }
  __shared__ float ss[4], qq[4];
  const int wave = threadIdx.x >> 6, lane = threadIdx.x & 63;
  if (lane == 0) { ss[wave] = s; qq[wave] = q; }
  __syncthreads();
  if (threadIdx.x == 0) {
    ws[PART_S + pb] = ss[0] + ss[1] + ss[2] + ss[3];
    ws[PART_Q + pb] = qq[0] + qq[1] + qq[2] + qq[3];
  }
}

// blocks 0..3: per-batch a/bb, bias, W1 fragments (normalization folded in).
// block 4: W2 fragments (scaled), batch-independent. Single bf16 (RNE).
__global__ __launch_bounds__(256) void prep_kernel(const float* __restrict__ W1,
                                                   const float* __restrict__ W2,
                                                   const float* __restrict__ scale,
                                                   const float* __restrict__ gamma,
                                                   const float* __restrict__ beta,
                                                   float* __restrict__ ws) {
  const int blk = blockIdx.x;
  if (blk == 4) {
    unsigned short* w2f = (unsigned short*)((char*)ws + W2F_BYTE);
    for (int e = threadIdx.x; e < 4096; e += 256) {
      const int j = e & 7, lane = (e >> 3) & 63, m = e >> 9;
      const int c = 16 * m + (lane & 15);
      const int r = (lane >> 4) * 8 + j;
      w2f[e] = bf16rne(W2[c * RR + r] * scale[c]);
    }
    return;
  }
  const int b = blk;
  __shared__ float aS[CCH], bbS[CCH];
  if (threadIdx.x < CCH) {
    const int c = threadIdx.x;
    const int bc = b * CCH + c;
    const float S = ws[PART_S + 2 * bc] + ws[PART_S + 2 * bc + 1];
    const float Q = ws[PART_Q + 2 * bc] + ws[PART_Q + 2 * bc + 1];
    const float mean = S / (float)S_SP;
    const float var  = Q / (float)S_SP - mean * mean;    // biased, matches ref
    const float rstd = rsqrtf(var + EPSV);
    const float a = rstd * gamma[c];
    aS[c]  = a;
    bbS[c] = beta[c] - mean * a;
  }
  __syncthreads();
  unsigned short* w1f = (unsigned short*)((char*)ws + W1F_BYTE + b * 8192);
  for (int e = threadIdx.x; e < 4096; e += 256) {
    const int j = e & 7, lane = (e >> 3) & 63;
    const int m = (e >> 9) & 1, kk = (e >> 10) & 3;
    const int r = 16 * m + (lane & 15);
    const int c = kk * 32 + (lane >> 4) * 8 + j;
    w1f[e] = bf16rne(W1[r * CCH + c] * aS[c]);
  }
  if (threadIdx.x < RR) {
    const int r = threadIdx.x;
    float sum = 0.f;
    for (int c = 0; c < CCH; ++c) sum += W1[r * CCH + c] * bbS[c];
    ws[BIAS_F + b * RR + r] = sum;
  }
}

// MFMA MLP, single-precision bf16 (error ~7e-3 << 0.131 threshold).
// Block = 256 thr (4 waves), tile = 128 c x 64 positions.
// GEMM1: proj(32xN) = W1a(32x128) @ x(128xN);  GEMM2: rec(128xN) = W2s(128x32) @ act.
// LDS: xs 32KB + act 8KB = 40960 -> 4 blocks/CU, 16 waves/CU.
__global__ __launch_bounds__(256, 4) void mlp_kernel(const float* __restrict__ x,
                                                     const float* __restrict__ ws,
                                                     float* __restrict__ out) {
  const int b = blockIdx.y;
  const int n0 = blockIdx.x * 64;
  const int tid = threadIdx.x;
  const int wave = tid >> 6, lane = tid & 63;
  const int g = lane >> 4, cl = lane & 15;
  const int bcol = wave * 16 + cl;

  __shared__ float xs[CCH][64];
  __shared__ uint32_t act32[4][RR * 16];

  const float* xb = x + (size_t)b * CCH * S_SP;

  // ---- A1 (W1) fragment loads ----
  const unsigned short* w1f = (const unsigned short*)((const char*)ws + W1F_BYTE + b * 8192);
  bf16x8 a1[4][2];   // [kk][m]
  #pragma unroll
  for (int kk = 0; kk < 4; ++kk)
    #pragma unroll
    for (int m = 0; m < 2; ++m)
      a1[kk][m] = *reinterpret_cast<const bf16x8*>(
          w1f + (size_t)(((kk * 2 + m)) * 64 + lane) * 8);

  // ---- bias -> acc1 init ----
  const float* biasp = ws + BIAS_F + b * RR;
  f32x4 acc1[2];
  #pragma unroll
  for (int m = 0; m < 2; ++m)
    #pragma unroll
    for (int q = 0; q < 4; ++q)
      acc1[m][q] = biasp[16 * m + 4 * g + q];

  // ---- stage x tile (fp32) into LDS, coalesced float4 ----
  #pragma unroll
  for (int k = 0; k < 8; ++k) {
    const int i = tid + 256 * k;
    const int row = i >> 4, c16 = i & 15;
    f32x4 v = *reinterpret_cast<const f32x4*>(xb + (size_t)row * S_SP + n0 + c16 * 4);
    *reinterpret_cast<f32x4*>(&xs[row][c16 * 4]) = v;
  }
  __syncthreads();

  // ---- GEMM1: 4 K-steps of 32; B built via RNE bf16 cast (cvt_pk) ----
  #pragma unroll
  for (int kk = 0; kk < 4; ++kk) {
    union { unsigned short s[8]; bf16x8 v; } bb;
    #pragma unroll
    for (int j = 0; j < 8; ++j)
      bb.s[j] = bf16rne(xs[kk * 32 + g * 8 + j][bcol]);
    #pragma unroll
    for (int m = 0; m < 2; ++m)
      acc1[m] = __builtin_amdgcn_mfma_f32_16x16x32_bf16(a1[kk][m], bb.v, acc1[m], 0, 0, 0);
  }

  // ---- ReLU6, bf16 in high 16 bits, exchange through LDS ----
  #pragma unroll
  for (int m = 0; m < 2; ++m)
    #pragma unroll
    for (int q = 0; q < 4; ++q) {
      const float a = fminf(fmaxf(acc1[m][q], 0.f), 6.f);
      const int r = 16 * m + 4 * g + q;
      act32[wave][r * 16 + cl] = ((uint32_t)bf16rne(a)) << 16;
    }
  __syncthreads();

  // ---- GEMM2 B-frag: act rows k = g*8+j at col cl, pack high halves ----
  uint32_t ua[8];
  #pragma unroll
  for (int j = 0; j < 8; ++j) ua[j] = act32[wave][(g * 8 + j) * 16 + cl];
  union { uint32_t u[4]; bf16x8 v; } bh2;
  #pragma unroll
  for (int jp = 0; jp < 4; ++jp)
    bh2.u[jp] = __builtin_amdgcn_perm(ua[2 * jp + 1], ua[2 * jp], 0x07060302u);

  // ---- GEMM2 + fused epilogue (residual + store) ----
  const unsigned short* w2f = (const unsigned short*)((const char*)ws + W2F_BYTE);
  float* ob = out + (size_t)b * CCH * S_SP + n0 + bcol;
  #pragma unroll
  for (int m = 0; m < 8; ++m) {
    const bf16x8 ah = *reinterpret_cast<const bf16x8*>(w2f + (size_t)(m * 64 + lane) * 8);
    f32x4 acc = {0.f, 0.f, 0.f, 0.f};
    acc = __builtin_amdgcn_mfma_f32_16x16x32_bf16(ah, bh2.v, acc, 0, 0, 0);
    #pragma unroll
    for (int q = 0; q < 4; ++q) {
      const int c = 16 * m + 4 * g + q;
      const float o = acc[q] + xs[c][bcol];
      __builtin_nontemporal_store(o, ob + (size_t)c * S_SP);
    }
  }
}

extern "C" void kernel_launch(void* const* d_in, const int* in_sizes, int n_in,
                              void* d_out, int out_size, void* d_ws, size_t ws_size,
                              hipStream_t stream) {
  const float* x     = (const float*)d_in[0];
  const float* scale = (const float*)d_in[1];
  const float* W1    = (const float*)d_in[2];
  const float* W2    = (const float*)d_in[3];
  const float* gamma = (const float*)d_in[4];
  const float* beta  = (const float*)d_in[5];
  float* out = (float*)d_out;
  float* ws  = (float*)d_ws;

  stats1_kernel<<<BATCH * CCH * 2, 256, 0, stream>>>(x, ws);
  prep_kernel<<<5, 256, 0, stream>>>(W1, W2, scale, gamma, beta, ws);
  dim3 grid(S_SP / 64, BATCH);
  mlp_kernel<<<grid, 256, 0, stream>>>(x, ws, out);
}

// Round 11
// 127.214 us; speedup vs baseline: 1.5755x; 1.1891x over previous
//
#include <hip/hip_runtime.h>
#include <math.h>
#include <stdint.h>

#define CCH 128
#define RR  32
#define S_SP 131072   // 32*64*64
#define BATCH 4
#define EPSV 1e-5f

typedef float f32x4 __attribute__((ext_vector_type(4)));
typedef short bf16x8 __attribute__((ext_vector_type(8)));

// ws layout:
// floats: [0,1024) PART_S, [1024,2048) PART_Q, [2048,2176) bias[b][32]
// bytes : W1F at 8704  : [b][kk][m][lane][j] bf16, 8192 B per batch (4 batches)
//         W2F at 41472 : [m][lane][j] bf16, 8192 B
#define PART_S 0
#define PART_Q 1024
#define BIAS_F 2048
#define W1F_BYTE 8704
#define W2F_BYTE 41472

__device__ __forceinline__ unsigned short bf16rne(float f) {
  return __builtin_bit_cast(unsigned short, (__bf16)f);
}

__global__ __launch_bounds__(256) void stats1_kernel(const float* __restrict__ x,
                                                     float* __restrict__ ws) {
  const int pb = blockIdx.x;
  const float* xp = x + (size_t)pb * (S_SP / 2);
  float s = 0.f, q = 0.f;
  for (int i = threadIdx.x * 4; i < S_SP / 2; i += 256 * 4) {
    float4 v = *reinterpret_cast<const float4*>(xp + i);
    s += v.x + v.y + v.z + v.w;
    q += v.x * v.x + v.y * v.y + v.z * v.z + v.w * v.w;
  }
  for (int off = 32; off > 0; off >>= 1) {
    s += __shfl_down(s, off, 64);
    q += __shfl_down(q, off, 64);
  }
  __shared__ float ss[4], qq[4];
  const int wave = threadIdx.x >> 6, lane = threadIdx.x & 63;
  if (lane == 0) { ss[wave] = s; qq[wave] = q; }
  __syncthreads();
  if (threadIdx.x == 0) {
    ws[PART_S + pb] = ss[0] + ss[1] + ss[2] + ss[3];
    ws[PART_Q + pb] = qq[0] + qq[1] + qq[2] + qq[3];
  }
}

// blocks 0..3: per-batch a/bb, bias, W1 fragments (normalization folded in).
// block 4: W2 fragments (scaled), batch-independent. Single bf16 (RNE).
__global__ __launch_bounds__(256) void prep_kernel(const float* __restrict__ W1,
                                                   const float* __restrict__ W2,
                                                   const float* __restrict__ scale,
                                                   const float* __restrict__ gamma,
                                                   const float* __restrict__ beta,
                                                   float* __restrict__ ws) {
  const int blk = blockIdx.x;
  if (blk == 4) {
    unsigned short* w2f = (unsigned short*)((char*)ws + W2F_BYTE);
    for (int e = threadIdx.x; e < 4096; e += 256) {
      const int j = e & 7, lane = (e >> 3) & 63, m = e >> 9;
      const int c = 16 * m + (lane & 15);
      const int r = (lane >> 4) * 8 + j;
      w2f[e] = bf16rne(W2[c * RR + r] * scale[c]);
    }
    return;
  }
  const int b = blk;
  __shared__ float aS[CCH], bbS[CCH];
  if (threadIdx.x < CCH) {
    const int c = threadIdx.x;
    const int bc = b * CCH + c;
    const float S = ws[PART_S + 2 * bc] + ws[PART_S + 2 * bc + 1];
    const float Q = ws[PART_Q + 2 * bc] + ws[PART_Q + 2 * bc + 1];
    const float mean = S / (float)S_SP;
    const float var  = Q / (float)S_SP - mean * mean;    // biased, matches ref
    const float rstd = rsqrtf(var + EPSV);
    const float a = rstd * gamma[c];
    aS[c]  = a;
    bbS[c] = beta[c] - mean * a;
  }
  __syncthreads();
  unsigned short* w1f = (unsigned short*)((char*)ws + W1F_BYTE + b * 8192);
  for (int e = threadIdx.x; e < 4096; e += 256) {
    const int j = e & 7, lane = (e >> 3) & 63;
    const int m = (e >> 9) & 1, kk = (e >> 10) & 3;
    const int r = 16 * m + (lane & 15);
    const int c = kk * 32 + (lane >> 4) * 8 + j;
    w1f[e] = bf16rne(W1[r * CCH + c] * aS[c]);
  }
  if (threadIdx.x < RR) {
    const int r = threadIdx.x;
    float sum = 0.f;
    for (int c = 0; c < CCH; ++c) sum += W1[r * CCH + c] * bbS[c];
    ws[BIAS_F + b * RR + r] = sum;
  }
}

// MFMA MLP, single bf16. Block = 256 thr (4 waves), tile = 128 c x 64 pos.
// GEMM1: proj(32xN) = W1a(32x128) @ x(128xN);  GEMM2: rec = W2s(128x32) @ act.
// Epilogue: residual added into xs IN PLACE (exact per-element ownership),
// then whole tile stored with coalesced float4 nt stores (256B row segments,
// 8 store insts/thread instead of 32 dword stores).
// LDS: xs 32KB + act 8KB = 40960 -> 4 blocks/CU, 16 waves/CU.
__global__ __launch_bounds__(256, 4) void mlp_kernel(const float* __restrict__ x,
                                                     const float* __restrict__ ws,
                                                     float* __restrict__ out) {
  const int b = blockIdx.y;
  const int n0 = blockIdx.x * 64;
  const int tid = threadIdx.x;
  const int wave = tid >> 6, lane = tid & 63;
  const int g = lane >> 4, cl = lane & 15;
  const int bcol = wave * 16 + cl;

  __shared__ float xs[CCH][64];
  __shared__ uint32_t act32[4][RR * 16];

  const float* xb = x + (size_t)b * CCH * S_SP;

  // ---- A1 (W1) fragment loads ----
  const unsigned short* w1f = (const unsigned short*)((const char*)ws + W1F_BYTE + b * 8192);
  bf16x8 a1[4][2];   // [kk][m]
  #pragma unroll
  for (int kk = 0; kk < 4; ++kk)
    #pragma unroll
    for (int m = 0; m < 2; ++m)
      a1[kk][m] = *reinterpret_cast<const bf16x8*>(
          w1f + (size_t)(((kk * 2 + m)) * 64 + lane) * 8);

  // ---- bias -> acc1 init ----
  const float* biasp = ws + BIAS_F + b * RR;
  f32x4 acc1[2];
  #pragma unroll
  for (int m = 0; m < 2; ++m)
    #pragma unroll
    for (int q = 0; q < 4; ++q)
      acc1[m][q] = biasp[16 * m + 4 * g + q];

  // ---- stage x tile (fp32) into LDS, coalesced float4 ----
  #pragma unroll
  for (int k = 0; k < 8; ++k) {
    const int i = tid + 256 * k;
    const int row = i >> 4, c16 = i & 15;
    f32x4 v = *reinterpret_cast<const f32x4*>(xb + (size_t)row * S_SP + n0 + c16 * 4);
    *reinterpret_cast<f32x4*>(&xs[row][c16 * 4]) = v;
  }
  __syncthreads();

  // ---- GEMM1: 4 K-steps of 32; B built via RNE bf16 cast ----
  #pragma unroll
  for (int kk = 0; kk < 4; ++kk) {
    union { unsigned short s[8]; bf16x8 v; } bb;
    #pragma unroll
    for (int j = 0; j < 8; ++j)
      bb.s[j] = bf16rne(xs[kk * 32 + g * 8 + j][bcol]);
    #pragma unroll
    for (int m = 0; m < 2; ++m)
      acc1[m] = __builtin_amdgcn_mfma_f32_16x16x32_bf16(a1[kk][m], bb.v, acc1[m], 0, 0, 0);
  }

  // ---- ReLU6, bf16 in high 16 bits, exchange through LDS (per-wave) ----
  #pragma unroll
  for (int m = 0; m < 2; ++m)
    #pragma unroll
    for (int q = 0; q < 4; ++q) {
      const float a = fminf(fmaxf(acc1[m][q], 0.f), 6.f);
      const int r = 16 * m + 4 * g + q;
      act32[wave][r * 16 + cl] = ((uint32_t)bf16rne(a)) << 16;
    }
  __syncthreads();

  // ---- GEMM2 B-frag: act rows k = g*8+j at col cl, pack high halves ----
  uint32_t ua[8];
  #pragma unroll
  for (int j = 0; j < 8; ++j) ua[j] = act32[wave][(g * 8 + j) * 16 + cl];
  union { uint32_t u[4]; bf16x8 v; } bh2;
  #pragma unroll
  for (int jp = 0; jp < 4; ++jp)
    bh2.u[jp] = __builtin_amdgcn_perm(ua[2 * jp + 1], ua[2 * jp], 0x07060302u);

  // ---- GEMM2 + residual added into xs in place ----
  const unsigned short* w2f = (const unsigned short*)((const char*)ws + W2F_BYTE);
  #pragma unroll
  for (int m = 0; m < 8; ++m) {
    const bf16x8 ah = *reinterpret_cast<const bf16x8*>(w2f + (size_t)(m * 64 + lane) * 8);
    f32x4 acc = {0.f, 0.f, 0.f, 0.f};
    acc = __builtin_amdgcn_mfma_f32_16x16x32_bf16(ah, bh2.v, acc, 0, 0, 0);
    #pragma unroll
    for (int q = 0; q < 4; ++q) {
      const int c = 16 * m + 4 * g + q;
      xs[c][bcol] += acc[q];      // single owner per (c,bcol): race-free RMW
    }
  }
  __syncthreads();

  // ---- coalesced nt store of the whole tile (float4, 256B row segments) ----
  float* obase = out + (size_t)b * CCH * S_SP + n0;
  #pragma unroll
  for (int k = 0; k < 8; ++k) {
    const int i = tid + 256 * k;
    const int row = i >> 4, c16 = i & 15;
    f32x4 v = *reinterpret_cast<const f32x4*>(&xs[row][c16 * 4]);
    __builtin_nontemporal_store(v,
        reinterpret_cast<f32x4*>(obase + (size_t)row * S_SP + c16 * 4));
  }
}

extern "C" void kernel_launch(void* const* d_in, const int* in_sizes, int n_in,
                              void* d_out, int out_size, void* d_ws, size_t ws_size,
                              hipStream_t stream) {
  const float* x     = (const float*)d_in[0];
  const float* scale = (const float*)d_in[1];
  const float* W1    = (const float*)d_in[2];
  const float* W2    = (const float*)d_in[3];
  const float* gamma = (const float*)d_in[4];
  const float* beta  = (const float*)d_in[5];
  float* out = (float*)d_out;
  float* ws  = (float*)d_ws;

  stats1_kernel<<<BATCH * CCH * 2, 256, 0, stream>>>(x, ws);
  prep_kernel<<<5, 256, 0, stream>>>(W1, W2, scale, gamma, beta, ws);
  dim3 grid(S_SP / 64, BATCH);
  mlp_kernel<<<grid, 256, 0, stream>>>(x, ws, out);
}